// Round 8
// baseline (81.376 us; speedup 1.0000x reference)
//
#include <hip/hip_runtime.h>
#include <hip/hip_bf16.h>

#define NPTS   300
#define HW_SZ  1920
#define NH     8
#define TOTAL  (NPTS * HW_SZ)    // 576000
#define NCOL   2400              // columns c = n*8 + h
#define L2T128 0.10381025293350249f   // log2(10000)/128

#define BM  64
#define BN  64
#define LDK 72                   // padded LDS k-stride (shorts)
#define SNP 129                  // sn/cn padded stride (floats)
#define WLP 17                   // wl padded row stride (floats)
#define MT  (HW_SZ / BM)         // 30
#define CT  38                   // 2432 / 64

typedef __attribute__((ext_vector_type(8))) short short8;
typedef __attribute__((ext_vector_type(4))) float floatx4;

__device__ __forceinline__ unsigned bf16_rne(float x) {
    unsigned u = __float_as_uint(x);
    return (u + 0x7fffu + ((u >> 16) & 1u)) >> 16;
}

// out[hw, c] = relu( sum_i cos(k_i ld)*P[i,c] + sin(k_i ld)*Q[i,c] + b[h] )
//   P = Ws*sin(k lp) + Wc*cos(k lp),  Q = Wc*sin(k lp) - Ws*cos(k lp)
// 64x64 tiles, 1140 blocks -> 4+ blocks/CU, 4 waves/SIMD (latency hiding).
__global__ __launch_bounds__(256, 4) void dre_fused3(const float* __restrict__ pd,
                                                     const float* __restrict__ dm,
                                                     const float* __restrict__ W,
                                                     const float* __restrict__ b,
                                                     float* __restrict__ out)
{
    __shared__ float kf[128];               //  0.5 KB
    __shared__ float ldm[BM];               // 0.25 KB
    __shared__ float sn[8 * SNP];           //  4.1 KB  sin(k_i lp(n)), 8 n's
    __shared__ float cn[8 * SNP];           //  4.1 KB
    __shared__ float wl[128 * WLP];         //  8.7 KB  W, stride-17 (conflict-free)
    __shared__ unsigned short As[BM * LDK]; //  9.2 KB
    __shared__ unsigned short Bs[BN * LDK]; //  9.2 KB   => ~36 KB, 4 blk/CU

    const int tid = threadIdx.x;
    const int m0  = blockIdx.x * BM;
    const int c0  = blockIdx.y * BN;
    const int n0  = c0 >> 3;                // 8 n's per block

    // ---- setup: kf, ldm, wl ----
    if (tid < 128)      kf[tid] = 100.0f * exp2f(-(float)tid * L2T128);
    else if (tid < 192) ldm[tid - 128] = __logf(dm[m0 + tid - 128] + 1e-5f);
    {
        const int i = tid >> 1, half = tid & 1;     // W row i, half-row
#pragma unroll
        for (int j = 0; j < 8; ++j)
            wl[i * WLP + half * 8 + j] = W[i * 16 + half * 8 + j];
    }
    __syncthreads();

    // ---- sn/cn for 8 n's (32 threads per n, 4 freqs each) ----
    {
        const int nl = tid >> 5;                    // 0..7
        const int nn = n0 + nl;
        const float pv = (nn < NPTS) ? pd[nn] : 0.0f;   // pad n masked at store
        const float lp = __logf(fmaxf(pv, 0.0f) + 1e-5f);
#pragma unroll
        for (int j = 0; j < 4; ++j) {
            const int i = (tid & 31) * 4 + j;
            float s, c;
            __sincosf(kf[i] * lp, &s, &c);          // |a| <= 1561 rad < 256 rev
            sn[nl * SNP + i] = s;
            cn[nl * SNP + i] = c;
        }
    }

    const int w    = tid >> 6;          // wave -> 16-row M strip
    const int lane = tid & 63;
    const int quad = lane >> 4;
    const int l16  = lane & 15;

    const int arow = tid >> 2;          // A staging: row 0..63
    const int akb  = (tid & 3) * 16;    //           16-wide k group (shorts)
    const int bcr  = tid >> 2;          // B staging: c row 0..63
    const int bkb  = (tid & 3) * 16;
    const int bnl  = bcr >> 3;
    const int bh   = bcr & 7;

    floatx4 acc[4];
#pragma unroll
    for (int nf = 0; nf < 4; ++nf) acc[nf] = (floatx4){0.f, 0.f, 0.f, 0.f};

    unsigned stash[2][8];               // packed sin for chunks 2/3

    __syncthreads();
    const float ld = ldm[arow];

    // K-chunks: ch 0,1 = cos(k_i ld), i in [0,64),[64,128); ch 2,3 = sin(same i).
#pragma unroll
    for (int ch = 0; ch < 4; ++ch) {
        const int ibase = (ch & 1) * 64;
        // ---- A tile (16 values/thread) ----
        if (ch < 2) {
            unsigned uc[8];
#pragma unroll
            for (int g = 0; g < 8; ++g) {
                const int i = ibase + akb + 2 * g;
                float s0, c0v, s1, c1v;
                __sincosf(kf[i] * ld,     &s0, &c0v);
                __sincosf(kf[i + 1] * ld, &s1, &c1v);
                uc[g]        = bf16_rne(c0v) | (bf16_rne(c1v) << 16);
                stash[ch][g] = bf16_rne(s0)  | (bf16_rne(s1)  << 16);
            }
            *(uint4*)&As[arow * LDK + akb]     = make_uint4(uc[0], uc[1], uc[2], uc[3]);
            *(uint4*)&As[arow * LDK + akb + 8] = make_uint4(uc[4], uc[5], uc[6], uc[7]);
        } else {
            const unsigned* st = stash[ch - 2];
            *(uint4*)&As[arow * LDK + akb]     = make_uint4(st[0], st[1], st[2], st[3]);
            *(uint4*)&As[arow * LDK + akb + 8] = make_uint4(st[4], st[5], st[6], st[7]);
        }
        // ---- B tile (16 values/thread): P for ch<2, Q for ch>=2 ----
        {
            unsigned uq[8];
#pragma unroll
            for (int g = 0; g < 8; ++g) {
                const int i = ibase + bkb + 2 * g;
                const float s0  = sn[bnl * SNP + i],     cc0 = cn[bnl * SNP + i];
                const float s1  = sn[bnl * SNP + i + 1], cc1 = cn[bnl * SNP + i + 1];
                const float ws0 = wl[i * WLP + bh],       wc0 = wl[i * WLP + 8 + bh];
                const float ws1 = wl[(i+1) * WLP + bh],   wc1 = wl[(i+1) * WLP + 8 + bh];
                float v0, v1;
                if (ch < 2) { v0 = ws0*s0 + wc0*cc0; v1 = ws1*s1 + wc1*cc1; }
                else        { v0 = wc0*s0 - ws0*cc0; v1 = wc1*s1 - ws1*cc1; }
                uq[g] = bf16_rne(v0) | (bf16_rne(v1) << 16);
            }
            *(uint4*)&Bs[bcr * LDK + bkb]     = make_uint4(uq[0], uq[1], uq[2], uq[3]);
            *(uint4*)&Bs[bcr * LDK + bkb + 8] = make_uint4(uq[4], uq[5], uq[6], uq[7]);
        }
        __syncthreads();

        // ---- MFMA (verified core; wave strip = 16 rows) ----
#pragma unroll
        for (int ks = 0; ks < 2; ++ks) {
            const int koff = ks * 32 + quad * 8;
            short8 a0 = *(const short8*)(&As[(w * 16 + l16) * LDK + koff]);
#pragma unroll
            for (int nf = 0; nf < 4; ++nf) {
                short8 bb = *(const short8*)(&Bs[(nf * 16 + l16) * LDK + koff]);
                acc[nf] = __builtin_amdgcn_mfma_f32_16x16x32_bf16(a0, bb, acc[nf], 0, 0, 0);
            }
        }
        __syncthreads();
    }

    // ---- epilogue (verified): C/D col=lane&15, row=quad*4+reg ----
    const float bias = b[lane & 7];
#pragma unroll
    for (int nf = 0; nf < 4; ++nf) {
        const int c = c0 + nf * 16 + l16;
        if (c < NCOL) {
            const int n = c >> 3, h = c & 7;
            const int hw = m0 + w * 16 + quad * 4;
            floatx4 v = acc[nf];
            v.x = fmaxf(v.x + bias, 0.0f);
            v.y = fmaxf(v.y + bias, 0.0f);
            v.z = fmaxf(v.z + bias, 0.0f);
            v.w = fmaxf(v.w + bias, 0.0f);
            *(floatx4*)(out + (size_t)h * TOTAL + (size_t)n * HW_SZ + hw) = v;
        }
    }
}

extern "C" void kernel_launch(void* const* d_in, const int* in_sizes, int n_in,
                              void* d_out, int out_size, void* d_ws, size_t ws_size,
                              hipStream_t stream) {
    const float* pd = (const float*)d_in[0];
    const float* dm = (const float*)d_in[1];
    const float* W  = (const float*)d_in[2];
    const float* b  = (const float*)d_in[3];
    float* out = (float*)d_out;

    dre_fused3<<<dim3(MT, CT), 256, 0, stream>>>(pd, dm, W, b, out);
}